// Round 7
// baseline (616.369 us; speedup 1.0000x reference)
//
#include <hip/hip_runtime.h>

#define LRELU_SLOPE 0.01f
#define BN_EPS 1e-5f

constexpr int B_ = 2, T_ = 8, Z_ = 16, Y_ = 32, X_ = 32;
constexpr int SP   = T_ * Z_ * Y_ * X_;   // 131072
constexpr int NPOS = B_ * SP;             // 262144
constexpr int Tp = 12, Zp = 20, Yp = 36, Xp = 36;   // padded dims (+2 each side)
constexpr int NCB  = 1024;                // conv blocks: b2 * t8 * z16 * yq4
constexpr size_t VOLE = (size_t)B_ * Tp * Zp * Yp * Xp * 16;  // shorts per 16-ch padded vol

typedef float v4f  __attribute__((ext_vector_type(4)));
typedef __bf16 v8bf __attribute__((ext_vector_type(8)));
typedef short  v8s  __attribute__((ext_vector_type(8)));

static __device__ __forceinline__ float bf2f(short s) {
    unsigned int u = ((unsigned int)(unsigned short)s) << 16;
    float f; __builtin_memcpy(&f, &u, 4); return f;
}
static __device__ __forceinline__ short f2bf(float f) {
    unsigned int u; __builtin_memcpy(&u, &f, 4);
    u += 0x7FFF + ((u >> 16) & 1);
    return (short)(u >> 16);
}
static __device__ __forceinline__ v4f mfma16(v8bf a, v8bf b, v4f c) {
    return __builtin_amdgcn_mfma_f32_16x16x32_bf16(a, b, c, 0, 0, 0);
}

// ------------------------------------------------------------ weight repacks
// W[co][ci16][625] fp32 -> WB[o 626][co][16ci] bf16 (o==625 = zero dummy)
__global__ void repack_bf16(const float* __restrict__ W, short* __restrict__ WB, int CO) {
    int i = blockIdx.x * 256 + threadIdx.x;
    int total = 626 * CO * 16;
    if (i >= total) return;
    int o = i / (CO * 16);
    int rr = i % (CO * 16);
    int co = rr / 16, ci = rr % 16;
    WB[i] = (o == 625) ? (short)0 : f2bf(W[((size_t)co * 16 + ci) * 625 + o]);
}
// W[co16][ci32][625] fp32 -> WB[o 625][co16][ci32] bf16
__global__ void repack32(const float* __restrict__ W, short* __restrict__ WB) {
    int i = blockIdx.x * 256 + threadIdx.x;
    int total = 625 * 16 * 32;
    if (i >= total) return;
    int o = i / (16 * 32);
    int rr = i % (16 * 32);
    int co = rr / 32, ci = rr % 32;
    WB[i] = f2bf(W[((size_t)co * 32 + ci) * 625 + o]);
}

// ------------------------------------------------------------ embed -> padded bf16 channel-last
__global__ void embed_kernel(const float* __restrict__ x, const float* __restrict__ wemb,
                             const float* __restrict__ bemb, short* __restrict__ outp) {
    int g = blockIdx.x * 256 + threadIdx.x;
    const float* xr = x + (size_t)g * 8;
    float xv[8];
#pragma unroll
    for (int f = 0; f < 8; ++f) xv[f] = xr[f];
    int xx = g & 31, yy = (g >> 5) & 31, zz = (g >> 10) & 15, tt = (g >> 14) & 7, bb = g >> 17;
    size_t addr = ((((size_t)(bb * Tp + tt + 2) * Zp + zz + 2) * Yp + yy + 2) * Xp + xx + 2) * 16;
    short ov[16];
#pragma unroll
    for (int c = 0; c < 16; ++c) {
        float a = bemb[c];
#pragma unroll
        for (int f = 0; f < 8; ++f) a = fmaf(xv[f], wemb[f * 16 + c], a);
        ov[c] = f2bf(a);
    }
    *(v8s*)(outp + addr)     = *(v8s*)ov;
    *(v8s*)(outp + addr + 8) = *(v8s*)(ov + 8);
}

// ------------------------------------------------------------ conv (CI=16, K = 2kx x 16ci)
// Block (256 thr, 4 waves) = (b,t,z,yq). Wave = (xh, yw): 16x x 4y. 25 slabs
// (kt,kz), each 12y x 36x x 16ci raw-copied to LDS (pads pre-zeroed).
// Bf groups (kxp) register-pipelined PD deep, issued BEFORE staging loads so
// vmcnt waits on Bf never drain the staging queue. Grid swizzle: blk&7 = t.
template <int NT, int PD, int MINW, bool OUT32>
__global__ __launch_bounds__(256, MINW) void conv_p16(
        const short* __restrict__ inp,   // 16-ch padded vol
        const short* __restrict__ wb,    // bf16 [626][CO][16]
        const float* __restrict__ bias,
        short* __restrict__ outp,        // OUT32 ? one 32-interleaved vol : NT 16-ch vols
        float* __restrict__ ps, float* __restrict__ psq) {
    constexpr int CO = NT * 16;
    constexpr int SLAB = 12 * 36 * 16;           // 6912 shorts
    __shared__ short As[SLAB + 16];
    __shared__ float lsum[32], lsq[32];

    const int tid = threadIdx.x;
    const int w = tid >> 6, lane = tid & 63;
    const int q = lane >> 4, m = lane & 15;
    const int xh = w & 1, yw = w >> 1;
    const int blk = blockIdx.x;
    const int t = blk & 7;
    const int loc = blk >> 3;
    const int yq = loc & 3, z = (loc >> 2) & 15, b = loc >> 6;

    const int ci0 = (q & 1) * 8;
    const int sel = q >> 1;

    if (tid < 2) *(v8s*)(As + SLAB + tid * 8) = (v8s){0,0,0,0,0,0,0,0};

    v4f acc[4][NT];
#pragma unroll
    for (int al = 0; al < 4; ++al)
#pragma unroll
        for (int nt = 0; nt < NT; ++nt) acc[al][nt] = (v4f){0.f, 0.f, 0.f, 0.f};

    auto slab_ok = [&](int s) -> bool {
        int kt = s / 5, kz = s % 5;
        int tt = t + kt, zz = z + kz;
        return tt >= 2 && tt < 10 && zz >= 2 && zz < 18;
    };
    v8s pf[4];
    auto load_pf = [&](int s) {
        int kt = s / 5, kz = s % 5;
        const short* gA = inp +
            (((size_t)(b * Tp + t + kt) * Zp + (z + kz)) * Yp + yq * 8) * (size_t)(Xp * 16);
#pragma unroll
        for (int r2 = 0; r2 < 4; ++r2) {
            int off = tid * 8 + r2 * 2048;
            if (off < SLAB) pf[r2] = *(const v8s*)(gA + off);
        }
    };
    auto write_pf = [&]() {
#pragma unroll
        for (int r2 = 0; r2 < 4; ++r2) {
            int off = tid * 8 + r2 * 2048;
            if (off < SLAB) *(v8s*)(As + off) = pf[r2];
        }
    };

    v8bf Bf[3][5][NT];
    auto loadB = [&](int s, int g) {
        const int kt = s / 5, kz = s % 5;
        const int obase = (kt * 5 + kz) * 25;
        const int kx0 = 2 * g;
#pragma unroll
        for (int ky = 0; ky < 5; ++ky) {
            const int o0 = obase + ky * 5 + kx0;
            const int od = (g < 2) ? 1 : (625 - o0);
            const int oq = o0 + sel * od;
#pragma unroll
            for (int nt = 0; nt < NT; ++nt)
                Bf[g][ky][nt] = *(const v8bf*)(wb + (size_t)oq * (CO * 16) +
                                               (nt * 16 + m) * 16 + ci0);
        }
    };

    if (slab_ok(0)) { load_pf(0); write_pf(); }
    __syncthreads();

#pragma unroll 1
    for (int s = 0; s < 25; ++s) {
        const bool ok = slab_ok(s);
        const bool nok = (s + 1 < 25) && slab_ok(s + 1);
        // Bf first (prefetch depth PD), THEN staging loads: vmcnt waits on Bf
        // retire before the staging queue, never behind it.
        if (ok) {
            loadB(s, 0);
            if (PD > 1) loadB(s, 1);
            if (PD > 2) loadB(s, 2);
        }
        if (nok) load_pf(s + 1);

        if (ok) {
#pragma unroll
            for (int g = 0; g < 3; ++g) {
                if (g + PD < 3) loadB(s, g + PD);
                const int kx0 = 2 * g;
                const int ax = xh * 16 + m + kx0 + sel;
#pragma unroll
                for (int rl = 0; rl < 8; ++rl) {
                    v8bf Af = *(const v8bf*)(As + ((yw * 4 + rl) * 36 + ax) * 16 + ci0);
#pragma unroll
                    for (int ky = 0; ky < 5; ++ky) {
                        const int al = rl - ky;
                        if (al >= 0 && al < 4) {
#pragma unroll
                            for (int nt = 0; nt < NT; ++nt)
                                acc[al][nt] = mfma16(Af, Bf[g][ky][nt], acc[al][nt]);
                        }
                    }
                }
            }
        }
        __syncthreads();
        if (nok) write_pf();
        __syncthreads();
    }

    // ---- epilogue
    if (tid < 32) { lsum[tid] = 0.f; lsq[tid] = 0.f; }
    __syncthreads();

    const int ybase = yq * 8 + yw * 4;
#pragma unroll
    for (int nt = 0; nt < NT; ++nt) {
        const int co = nt * 16 + m;
        const float bv = bias[co];
        float s = 0.f, sq = 0.f;
#pragma unroll
        for (int al = 0; al < 4; ++al) {
            size_t orow;
            if (OUT32) {
                orow = ((((size_t)(b * Tp + t + 2) * Zp + (z + 2)) * Yp +
                         (ybase + al + 2)) * Xp + (xh * 16 + 2)) * 32;
            } else {
                orow = (size_t)nt * VOLE +
                    ((((size_t)(b * Tp + t + 2) * Zp + (z + 2)) * Yp +
                      (ybase + al + 2)) * Xp + (xh * 16 + 2)) * 16;
            }
#pragma unroll
            for (int rg = 0; rg < 4; ++rg) {
                float v = acc[al][nt][rg] + bv;
                if (OUT32) outp[orow + (size_t)(q * 4 + rg) * 32 + co] = f2bf(v);
                else       outp[orow + (size_t)(q * 4 + rg) * 16 + m]  = f2bf(v);
                s += v; sq += v * v;
            }
        }
        s += __shfl_down(s, 32, 64);  sq += __shfl_down(sq, 32, 64);
        s += __shfl_down(s, 16, 64);  sq += __shfl_down(sq, 16, 64);
        if (lane < 16) { atomicAdd(&lsum[co], s); atomicAdd(&lsq[co], sq); }
    }
    __syncthreads();
    if (tid < CO) {
        ps[(size_t)tid * NCB + blk]  = lsum[tid];
        psq[(size_t)tid * NCB + blk] = lsq[tid];
    }
}

// ------------------------------------------------------------ conv3 (CI=32 interleaved, K = 32ci)
// Same block/wave structure; input one 32-interleaved vol; 25 slabs of
// 12y x 36x x 32ci (27.6 KB); 5 clean kx groups (no dummy), Bf pipelined 2 deep.
__global__ __launch_bounds__(256, 3) void conv_c32(
        const short* __restrict__ inp,   // 32-interleaved padded vol
        const short* __restrict__ wb,    // bf16 [625][16co][32ci]
        const float* __restrict__ bias,
        short* __restrict__ outp,        // one 16-ch padded vol
        float* __restrict__ ps, float* __restrict__ psq) {
    constexpr int SLAB = 12 * 36 * 32;           // 13824 shorts
    __shared__ short As[SLAB + 16];
    __shared__ float lsum[32], lsq[32];

    const int tid = threadIdx.x;
    const int w = tid >> 6, lane = tid & 63;
    const int q = lane >> 4, m = lane & 15;
    const int xh = w & 1, yw = w >> 1;
    const int blk = blockIdx.x;
    const int t = blk & 7;
    const int loc = blk >> 3;
    const int yq = loc & 3, z = (loc >> 2) & 15, b = loc >> 6;

    if (tid < 2) *(v8s*)(As + SLAB + tid * 8) = (v8s){0,0,0,0,0,0,0,0};

    v4f acc[4];
#pragma unroll
    for (int al = 0; al < 4; ++al) acc[al] = (v4f){0.f, 0.f, 0.f, 0.f};

    auto slab_ok = [&](int s) -> bool {
        int kt = s / 5, kz = s % 5;
        int tt = t + kt, zz = z + kz;
        return tt >= 2 && tt < 10 && zz >= 2 && zz < 18;
    };
    v8s pf[7];
    auto load_pf = [&](int s) {
        int kt = s / 5, kz = s % 5;
        const short* gA = inp +
            (((size_t)(b * Tp + t + kt) * Zp + (z + kz)) * Yp + yq * 8) * (size_t)(Xp * 32);
#pragma unroll
        for (int r2 = 0; r2 < 7; ++r2) {
            int off = tid * 8 + r2 * 2048;
            if (off < SLAB) pf[r2] = *(const v8s*)(gA + off);
        }
    };
    auto write_pf = [&]() {
#pragma unroll
        for (int r2 = 0; r2 < 7; ++r2) {
            int off = tid * 8 + r2 * 2048;
            if (off < SLAB) *(v8s*)(As + off) = pf[r2];
        }
    };

    v8bf Bf[3][5];                               // 3 slots, pipeline depth 2
    auto loadB = [&](int s, int kx, int slot) {
        const int kt = s / 5, kz = s % 5;
        const int obase = (kt * 5 + kz) * 25;
#pragma unroll
        for (int ky = 0; ky < 5; ++ky)
            Bf[slot][ky] = *(const v8bf*)(wb + (size_t)(obase + ky * 5 + kx) * (16 * 32) +
                                          m * 32 + q * 8);
    };

    if (slab_ok(0)) { load_pf(0); write_pf(); }
    __syncthreads();

#pragma unroll 1
    for (int s = 0; s < 25; ++s) {
        const bool ok = slab_ok(s);
        const bool nok = (s + 1 < 25) && slab_ok(s + 1);
        if (ok) { loadB(s, 0, 0); loadB(s, 1, 1); }
        if (nok) load_pf(s + 1);

        if (ok) {
#pragma unroll
            for (int kx = 0; kx < 5; ++kx) {
                if (kx + 2 < 5) loadB(s, kx + 2, (kx + 2) % 3);
                const int ax = xh * 16 + m + kx;
#pragma unroll
                for (int rl = 0; rl < 8; ++rl) {
                    v8bf Af = *(const v8bf*)(As + ((yw * 4 + rl) * 36 + ax) * 32 + q * 8);
#pragma unroll
                    for (int ky = 0; ky < 5; ++ky) {
                        const int al = rl - ky;
                        if (al >= 0 && al < 4)
                            acc[al] = mfma16(Af, Bf[kx % 3][ky], acc[al]);
                    }
                }
            }
        }
        __syncthreads();
        if (nok) write_pf();
        __syncthreads();
    }

    // ---- epilogue
    if (tid < 32) { lsum[tid] = 0.f; lsq[tid] = 0.f; }
    __syncthreads();

    const int ybase = yq * 8 + yw * 4;
    {
        const float bv = bias[m];
        float s = 0.f, sq = 0.f;
#pragma unroll
        for (int al = 0; al < 4; ++al) {
            const size_t orow =
                ((((size_t)(b * Tp + t + 2) * Zp + (z + 2)) * Yp +
                  (ybase + al + 2)) * Xp + (xh * 16 + 2)) * 16;
#pragma unroll
            for (int rg = 0; rg < 4; ++rg) {
                float v = acc[al][rg] + bv;
                outp[orow + (size_t)(q * 4 + rg) * 16 + m] = f2bf(v);
                s += v; sq += v * v;
            }
        }
        s += __shfl_down(s, 32, 64);  sq += __shfl_down(sq, 32, 64);
        s += __shfl_down(s, 16, 64);  sq += __shfl_down(sq, 16, 64);
        if (lane < 16) { atomicAdd(&lsum[m], s); atomicAdd(&lsq[m], sq); }
    }
    __syncthreads();
    if (tid < 16) {
        ps[(size_t)tid * NCB + blk]  = lsum[tid];
        psq[(size_t)tid * NCB + blk] = lsq[tid];
    }
}

// ------------------------------------------------------------ bn stats
__global__ void stats_kernel(const float* __restrict__ ps, const float* __restrict__ psq,
                             const float* __restrict__ g, const float* __restrict__ beta,
                             float* __restrict__ scale, float* __restrict__ shift) {
    int co = blockIdx.x;
    int tid = threadIdx.x;
    float s = 0.f, q = 0.f;
    for (int i = tid; i < NCB; i += 256) {
        s += ps[(size_t)co * NCB + i];
        q += psq[(size_t)co * NCB + i];
    }
#pragma unroll
    for (int off = 32; off >= 1; off >>= 1) {
        s += __shfl_down(s, off, 64);
        q += __shfl_down(q, off, 64);
    }
    __shared__ float ss[4], qq[4];
    int w = tid >> 6, lane = tid & 63;
    if (lane == 0) { ss[w] = s; qq[w] = q; }
    __syncthreads();
    if (tid == 0) {
        float S = ss[0] + ss[1] + ss[2] + ss[3];
        float Q = qq[0] + qq[1] + qq[2] + qq[3];
        float mn = S / (float)NPOS;
        float var = Q / (float)NPOS - mn * mn;
        float rstd = rsqrtf(var + BN_EPS);
        float sc = g[co] * rstd;
        scale[co] = sc;
        shift[co] = beta[co] - mn * sc;
    }
}

// ------------------------------------------------------------ bn + leaky relu, interior in-place
template <int C>
__global__ void bn_lrelu(short* __restrict__ vol, const float* __restrict__ scale,
                         const float* __restrict__ shift) {
    int gid = blockIdx.x * 256 + threadIdx.x;    // NPOS * C/8 ids
    int p = gid / (C / 8);
    int cg = (gid % (C / 8)) * 8;
    int xx = p & 31, yy = (p >> 5) & 31, zz = (p >> 10) & 15, tt = (p >> 14) & 7, bb = p >> 17;
    size_t addr = ((((size_t)(bb * Tp + tt + 2) * Zp + zz + 2) * Yp + yy + 2) * Xp + xx + 2) * C + cg;
    v8s v = *(v8s*)(vol + addr);
    short o[8];
#pragma unroll
    for (int j = 0; j < 8; ++j) {
        float f = bf2f(v[j]) * scale[cg + j] + shift[cg + j];
        f = f > 0.f ? f : LRELU_SLOPE * f;
        o[j] = f2bf(f);
    }
    *(v8s*)(vol + addr) = *(v8s*)o;
}

// ------------------------------------------------------------ final: bn3 + lrelu + projection
__global__ void bnproj_kernel(const short* __restrict__ h, const float* __restrict__ scale,
                              const float* __restrict__ shift, const float* __restrict__ wp,
                              const float* __restrict__ bp, float* __restrict__ out) {
    int g = blockIdx.x * 256 + threadIdx.x;
    int xx = g & 31, yy = (g >> 5) & 31, zz = (g >> 10) & 15, tt = (g >> 14) & 7, bb = g >> 17;
    size_t addr = ((((size_t)(bb * Tp + tt + 2) * Zp + zz + 2) * Yp + yy + 2) * Xp + xx + 2) * 16;
    v8s lo = *(const v8s*)(h + addr);
    v8s hi = *(const v8s*)(h + addr + 8);
    float a = bp[0];
#pragma unroll
    for (int j = 0; j < 8; ++j) {
        float f = bf2f(lo[j]) * scale[j] + shift[j];
        f = f > 0.f ? f : LRELU_SLOPE * f;
        a = fmaf(f, wp[j], a);
    }
#pragma unroll
    for (int j = 0; j < 8; ++j) {
        float f = bf2f(hi[j]) * scale[8 + j] + shift[8 + j];
        f = f > 0.f ? f : LRELU_SLOPE * f;
        a = fmaf(f, wp[8 + j], a);
    }
    out[g] = a;
}

// ------------------------------------------------------------ launch
extern "C" void kernel_launch(void* const* d_in, const int* in_sizes, int n_in,
                              void* d_out, int out_size, void* d_ws, size_t ws_size,
                              hipStream_t stream) {
    const float* x    = (const float*)d_in[0];
    const float* wemb = (const float*)d_in[1];
    const float* bemb = (const float*)d_in[2];
    const float* W1   = (const float*)d_in[3];
    const float* b1   = (const float*)d_in[4];
    const float* g1   = (const float*)d_in[5];
    const float* be1  = (const float*)d_in[6];
    const float* W2   = (const float*)d_in[7];
    const float* b2   = (const float*)d_in[8];
    const float* g2   = (const float*)d_in[9];
    const float* be2  = (const float*)d_in[10];
    const float* W3   = (const float*)d_in[11];
    const float* b3   = (const float*)d_in[12];
    const float* g3   = (const float*)d_in[13];
    const float* be3  = (const float*)d_in[14];
    const float* wp   = (const float*)d_in[15];
    const float* bp   = (const float*)d_in[16];

    char* base = (char*)d_ws;
    short* PA   = (short*)(base);                  // 16-ch vol: 19,906,560 B
    short* PB   = (short*)(base + 19906560);       // 16-ch vol: 19,906,560 B
    short* P32  = (short*)(base + 39813120);       // 32-interleaved vol: 39,813,120 B
    short* WB1  = (short*)(base + 79626240);       // 320,512 B
    short* WB2  = (short*)(base + 79946752);       // 641,024 B
    short* WB3  = (short*)(base + 80587776);       // 640,000 B
    float* ps   = (float*)(base + 81228800);       // 32*1024*4 = 131,072 B
    float* psq  = (float*)(base + 81359872);       // 131,072 B
    float* sc1  = (float*)(base + 81490944);       // 128 B each
    float* sh1  = (float*)(base + 81491072);
    float* sc2  = (float*)(base + 81491200);
    float* sh2  = (float*)(base + 81491328);
    float* sc3  = (float*)(base + 81491456);
    float* sh3  = (float*)(base + 81491584);

    // zero all padded activation volumes (pads must be 0 every call)
    hipMemsetAsync(base, 0, 79626240, stream);

    repack_bf16<<<(626 * 16 * 16 + 255) / 256, 256, 0, stream>>>(W1, WB1, 16);
    repack_bf16<<<(626 * 32 * 16 + 255) / 256, 256, 0, stream>>>(W2, WB2, 32);
    repack32<<<(625 * 16 * 32 + 255) / 256, 256, 0, stream>>>(W3, WB3);

    embed_kernel<<<NPOS / 256, 256, 0, stream>>>(x, wemb, bemb, PA);

    // layer 1: 16 -> 16  (PD=3: all Bf groups preloaded; 4 blocks/CU)
    conv_p16<1, 3, 4, false><<<NCB, 256, 0, stream>>>(PA, WB1, b1, PB, ps, psq);
    stats_kernel<<<16, 256, 0, stream>>>(ps, psq, g1, be1, sc1, sh1);
    bn_lrelu<16><<<NPOS * 2 / 256, 256, 0, stream>>>(PB, sc1, sh1);

    // layer 2: 16 -> 32  (PD=1 pipeline; out = 32-interleaved vol; 3 blocks/CU)
    conv_p16<2, 1, 3, true><<<NCB, 256, 0, stream>>>(PB, WB2, b2, P32, ps, psq);
    stats_kernel<<<32, 256, 0, stream>>>(ps, psq, g2, be2, sc2, sh2);
    bn_lrelu<32><<<NPOS * 4 / 256, 256, 0, stream>>>(P32, sc2, sh2);

    // layer 3: 32 -> 16  (K=32ci, clean 5-kx groups, PD=2; 3 blocks/CU)
    conv_c32<<<NCB, 256, 0, stream>>>(P32, WB3, b3, PA, ps, psq);
    stats_kernel<<<16, 256, 0, stream>>>(ps, psq, g3, be3, sc3, sh3);

    // BN3 + lrelu + projection
    bnproj_kernel<<<NPOS / 256, 256, 0, stream>>>(PA, sc3, sh3, wp, bp, (float*)d_out);
}

// Round 8
// 611.752 us; speedup vs baseline: 1.0075x; 1.0075x over previous
//
#include <hip/hip_runtime.h>

#define LRELU_SLOPE 0.01f
#define BN_EPS 1e-5f

constexpr int B_ = 2, T_ = 8, Z_ = 16, Y_ = 32, X_ = 32;
constexpr int SP   = T_ * Z_ * Y_ * X_;   // 131072
constexpr int NPOS = B_ * SP;             // 262144
constexpr int Tp = 12, Zp = 20, Yp = 36, Xp = 36;   // padded dims (+2 each side)
constexpr int NCB  = 1024;                // conv blocks: b2 * t8 * z16 * yq4
constexpr size_t VOLE = (size_t)B_ * Tp * Zp * Yp * Xp * 16;  // shorts per 16-ch padded vol

typedef float v4f  __attribute__((ext_vector_type(4)));
typedef __bf16 v8bf __attribute__((ext_vector_type(8)));
typedef short  v8s  __attribute__((ext_vector_type(8)));

static __device__ __forceinline__ float bf2f(short s) {
    unsigned int u = ((unsigned int)(unsigned short)s) << 16;
    float f; __builtin_memcpy(&f, &u, 4); return f;
}
static __device__ __forceinline__ short f2bf(float f) {
    unsigned int u; __builtin_memcpy(&u, &f, 4);
    u += 0x7FFF + ((u >> 16) & 1);
    return (short)(u >> 16);
}
static __device__ __forceinline__ v4f mfma16(v8bf a, v8bf b, v4f c) {
    return __builtin_amdgcn_mfma_f32_16x16x32_bf16(a, b, c, 0, 0, 0);
}

// ------------------------------------------------------------ weight repack
// W[co][ci][625] fp32 -> WB[cih][o 626][co][16ci] bf16 (o==625 = zero block)
__global__ void repack_bf16(const float* __restrict__ W, short* __restrict__ WB,
                            int CO, int CIH) {
    int i = blockIdx.x * 256 + threadIdx.x;
    int total = CIH * 626 * CO * 16;
    if (i >= total) return;
    int cih = i / (626 * CO * 16);
    int r   = i % (626 * CO * 16);
    int o   = r / (CO * 16);
    int rr  = r % (CO * 16);
    int co = rr / 16, cil = rr % 16;
    WB[i] = (o == 625) ? (short)0
          : f2bf(W[((size_t)co * (CIH * 16) + cih * 16 + cil) * 625 + o]);
}

// ------------------------------------------------------------ embed -> padded bf16 channel-last
__global__ void embed_kernel(const float* __restrict__ x, const float* __restrict__ wemb,
                             const float* __restrict__ bemb, short* __restrict__ outp) {
    int g = blockIdx.x * 256 + threadIdx.x;
    const float* xr = x + (size_t)g * 8;
    float xv[8];
#pragma unroll
    for (int f = 0; f < 8; ++f) xv[f] = xr[f];
    int xx = g & 31, yy = (g >> 5) & 31, zz = (g >> 10) & 15, tt = (g >> 14) & 7, bb = g >> 17;
    size_t addr = ((((size_t)(bb * Tp + tt + 2) * Zp + zz + 2) * Yp + yy + 2) * Xp + xx + 2) * 16;
    short ov[16];
#pragma unroll
    for (int c = 0; c < 16; ++c) {
        float a = bemb[c];
#pragma unroll
        for (int f = 0; f < 8; ++f) a = fmaf(xv[f], wemb[f * 16 + c], a);
        ov[c] = f2bf(a);
    }
    *(v8s*)(outp + addr)     = *(v8s*)ov;
    *(v8s*)(outp + addr + 8) = *(v8s*)(ov + 8);
}

// ------------------------------------------------------------ conv4d: dual-plane LDS phases
// Block (256 thr, 4 waves) = (b,t,z,yq): out y in [yq*8,+8), x 0..31, all CO.
// Jobs j = (kt,kz)[,cih]: NJ = 25*CIH planes of 12y x 36x x 16ci, raw-copied
// into LDS (pads pre-zeroed in global). TWO planes per barrier pair (halves
// phase count vs 1-plane): compute(j0) -> stage-loads(next pair) -> compute(j1)
// -> sync -> LDS writes -> sync. Wave = (xh, yw): 16x x 4y. blk&7 = t (XCD).
template <int CI, int CO>
__global__ __launch_bounds__(256, 4) void conv_mfma(
        const short* __restrict__ inp,   // CIH padded vols, stride VOLE
        const short* __restrict__ wb,    // bf16 [CIH][626][CO][16]
        const float* __restrict__ bias,
        short* __restrict__ outp,        // NT padded vols, stride VOLE
        float* __restrict__ ps, float* __restrict__ psq) {
    constexpr int NT = CO / 16;
    constexpr int CIH = CI / 16;
    constexpr int NJ = 25 * CIH;
    constexpr int SLAB = 12 * 36 * 16;           // 6912 shorts
    constexpr int SLABP = SLAB + 16;             // +16: dummy-lane read overflow
    __shared__ short As[2 * SLABP];
    __shared__ float lsum[32], lsq[32];

    const int tid = threadIdx.x;
    const int w = tid >> 6, lane = tid & 63;
    const int q = lane >> 4, m = lane & 15;
    const int xh = w & 1, yw = w >> 1;
    const int blk = blockIdx.x;
    const int t = blk & 7;                       // XCD swizzle
    const int loc = blk >> 3;
    const int yq = loc & 3, z = (loc >> 2) & 15, b = loc >> 6;

    const int ci0 = (q & 1) * 8;
    const int sel = q >> 1;

    if (tid < 4) *(v8s*)(As + (tid >> 1) * SLABP + SLAB + (tid & 1) * 8) =
        (v8s){0,0,0,0,0,0,0,0};

    v4f acc[4][NT];
#pragma unroll
    for (int al = 0; al < 4; ++al)
#pragma unroll
        for (int nt = 0; nt < NT; ++nt) acc[al][nt] = (v4f){0.f, 0.f, 0.f, 0.f};

    auto jdec = [&](int j, int& cih, int& kt, int& kz) {
        int sl = (CIH == 2) ? (j >> 1) : j;
        cih = (CIH == 2) ? (j & 1) : 0;
        kt = sl / 5; kz = sl % 5;
    };
    auto job_ok = [&](int j) -> bool {
        int cih, kt, kz; jdec(j, cih, kt, kz);
        int tt = t + kt, zz = z + kz;
        return tt >= 2 && tt < 10 && zz >= 2 && zz < 18;
    };
    v8s pf[2][4];
    auto load_pf = [&](int j, int slot) {
        int cih, kt, kz; jdec(j, cih, kt, kz);
        const short* gA = inp + (size_t)cih * VOLE +
            (((size_t)(b * Tp + t + kt) * Zp + (z + kz)) * Yp + yq * 8) * (size_t)(Xp * 16);
#pragma unroll
        for (int r2 = 0; r2 < 4; ++r2) {
            int off = tid * 8 + r2 * 2048;
            if (off < SLAB) pf[slot][r2] = *(const v8s*)(gA + off);
        }
    };
    auto write_pf = [&](int slot) {
#pragma unroll
        for (int r2 = 0; r2 < 4; ++r2) {
            int off = tid * 8 + r2 * 2048;
            if (off < SLAB) *(v8s*)(As + slot * SLABP + off) = pf[slot][r2];
        }
    };
    auto compute = [&](int j, int slot) {
        int cih, kt, kz; jdec(j, cih, kt, kz);
        const int obase = (kt * 5 + kz) * 25;
        const short* wbc = wb + (size_t)cih * 626 * (CO * 16);
        const short* Ab = As + slot * SLABP;
#pragma unroll
        for (int g = 0; g < 3; ++g) {
            const int kx0 = 2 * g;
            v8bf Bf[5][NT];
#pragma unroll
            for (int ky = 0; ky < 5; ++ky) {
                const int o0 = obase + ky * 5 + kx0;
                const int od = (g < 2) ? 1 : (625 - o0);
                const int oq = o0 + sel * od;
#pragma unroll
                for (int nt = 0; nt < NT; ++nt)
                    Bf[ky][nt] = *(const v8bf*)(wbc + (size_t)oq * (CO * 16) +
                                                (nt * 16 + m) * 16 + ci0);
            }
            const int ax = xh * 16 + m + kx0 + sel;
#pragma unroll
            for (int rl = 0; rl < 8; ++rl) {
                v8bf Af = *(const v8bf*)(Ab + ((yw * 4 + rl) * 36 + ax) * 16 + ci0);
#pragma unroll
                for (int ky = 0; ky < 5; ++ky) {
                    const int al = rl - ky;
                    if (al >= 0 && al < 4) {
#pragma unroll
                        for (int nt = 0; nt < NT; ++nt)
                            acc[al][nt] = mfma16(Af, Bf[ky][nt], acc[al][nt]);
                    }
                }
            }
        }
    };

    // prologue: stage jobs 0,1
    {
        const bool ok0 = job_ok(0);
        const bool ok1 = (NJ > 1) && job_ok(1);
        if (ok0) load_pf(0, 0);
        if (ok1) load_pf(1, 1);
        if (ok0) write_pf(0);
        if (ok1) write_pf(1);
    }
    __syncthreads();

#pragma unroll 1
    for (int p = 0; p < (NJ + 1) / 2; ++p) {
        const int j0 = 2 * p, j1 = 2 * p + 1;
        const int n0 = j0 + 2, n1 = j1 + 2;
        const bool v0 = job_ok(j0);
        const bool v1 = (j1 < NJ) && job_ok(j1);
        const bool w0 = (n0 < NJ) && job_ok(n0);
        const bool w1 = (n1 < NJ) && job_ok(n1);

        if (v0) compute(j0, 0);
        // staging loads issued mid-phase: a half-phase of MFMA (~2300 cyc)
        // covers their latency, and only j1's Bf waits can drain them.
        if (w0) load_pf(n0, 0);
        if (w1) load_pf(n1, 1);
        if (v1) compute(j1, 1);
        __syncthreads();
        if (w0) write_pf(0);
        if (w1) write_pf(1);
        __syncthreads();
    }

    // ---- epilogue: bias, bf16 store (raw) to NT padded vols, block stats
    if (tid < 32) { lsum[tid] = 0.f; lsq[tid] = 0.f; }
    __syncthreads();

    const int ybase = yq * 8 + yw * 4;
#pragma unroll
    for (int nt = 0; nt < NT; ++nt) {
        const int co = nt * 16 + m;
        const float bv = bias[co];
        float s = 0.f, sq = 0.f;
#pragma unroll
        for (int al = 0; al < 4; ++al) {
            const size_t orow = (size_t)nt * VOLE +
                ((((size_t)(b * Tp + t + 2) * Zp + (z + 2)) * Yp +
                  (ybase + al + 2)) * Xp + (xh * 16 + 2)) * 16;
#pragma unroll
            for (int rg = 0; rg < 4; ++rg) {
                float v = acc[al][nt][rg] + bv;
                outp[orow + (size_t)(q * 4 + rg) * 16 + m] = f2bf(v);
                s += v; sq += v * v;
            }
        }
        s += __shfl_down(s, 32, 64);  sq += __shfl_down(sq, 32, 64);
        s += __shfl_down(s, 16, 64);  sq += __shfl_down(sq, 16, 64);
        if (lane < 16) { atomicAdd(&lsum[co], s); atomicAdd(&lsq[co], sq); }
    }
    __syncthreads();
    if (tid < CO) {
        ps[(size_t)tid * NCB + blk]  = lsum[tid];
        psq[(size_t)tid * NCB + blk] = lsq[tid];
    }
}

// ------------------------------------------------------------ bn stats: fold into scale/shift
__global__ void stats_kernel(const float* __restrict__ ps, const float* __restrict__ psq,
                             const float* __restrict__ g, const float* __restrict__ beta,
                             float* __restrict__ scale, float* __restrict__ shift) {
    int co = blockIdx.x;
    int tid = threadIdx.x;
    float s = 0.f, q = 0.f;
    for (int i = tid; i < NCB; i += 256) {
        s += ps[(size_t)co * NCB + i];
        q += psq[(size_t)co * NCB + i];
    }
#pragma unroll
    for (int off = 32; off >= 1; off >>= 1) {
        s += __shfl_down(s, off, 64);
        q += __shfl_down(q, off, 64);
    }
    __shared__ float ss[4], qq[4];
    int w = tid >> 6, lane = tid & 63;
    if (lane == 0) { ss[w] = s; qq[w] = q; }
    __syncthreads();
    if (tid == 0) {
        float S = ss[0] + ss[1] + ss[2] + ss[3];
        float Q = qq[0] + qq[1] + qq[2] + qq[3];
        float mn = S / (float)NPOS;
        float var = Q / (float)NPOS - mn * mn;
        float rstd = rsqrtf(var + BN_EPS);
        float sc = g[co] * rstd;
        scale[co] = sc;
        shift[co] = beta[co] - mn * sc;
    }
}

// ------------------------------------------------------------ bn + leaky relu, in-place interior of one 16-ch vol
__global__ void bn_lrelu16(short* __restrict__ vol, const float* __restrict__ scale,
                           const float* __restrict__ shift, int coff) {
    int g = blockIdx.x * 256 + threadIdx.x;      // 0..2*NPOS-1
    int half = g & 1, p = g >> 1;
    int xx = p & 31, yy = (p >> 5) & 31, zz = (p >> 10) & 15, tt = (p >> 14) & 7, bb = p >> 17;
    size_t addr = ((((size_t)(bb * Tp + tt + 2) * Zp + zz + 2) * Yp + yy + 2) * Xp + xx + 2) * 16
                + half * 8;
    const int c0 = coff + half * 8;
    v8s v = *(v8s*)(vol + addr);
    short o[8];
#pragma unroll
    for (int j = 0; j < 8; ++j) {
        float f = bf2f(v[j]) * scale[c0 + j] + shift[c0 + j];
        f = f > 0.f ? f : LRELU_SLOPE * f;
        o[j] = f2bf(f);
    }
    *(v8s*)(vol + addr) = *(v8s*)o;
}

// ------------------------------------------------------------ final: bn3 + lrelu + projection
__global__ void bnproj_kernel(const short* __restrict__ h, const float* __restrict__ scale,
                              const float* __restrict__ shift, const float* __restrict__ wp,
                              const float* __restrict__ bp, float* __restrict__ out) {
    int g = blockIdx.x * 256 + threadIdx.x;
    int xx = g & 31, yy = (g >> 5) & 31, zz = (g >> 10) & 15, tt = (g >> 14) & 7, bb = g >> 17;
    size_t addr = ((((size_t)(bb * Tp + tt + 2) * Zp + zz + 2) * Yp + yy + 2) * Xp + xx + 2) * 16;
    v8s lo = *(const v8s*)(h + addr);
    v8s hi = *(const v8s*)(h + addr + 8);
    float a = bp[0];
#pragma unroll
    for (int j = 0; j < 8; ++j) {
        float f = bf2f(lo[j]) * scale[j] + shift[j];
        f = f > 0.f ? f : LRELU_SLOPE * f;
        a = fmaf(f, wp[j], a);
    }
#pragma unroll
    for (int j = 0; j < 8; ++j) {
        float f = bf2f(hi[j]) * scale[8 + j] + shift[8 + j];
        f = f > 0.f ? f : LRELU_SLOPE * f;
        a = fmaf(f, wp[8 + j], a);
    }
    out[g] = a;
}

// ------------------------------------------------------------ launch
extern "C" void kernel_launch(void* const* d_in, const int* in_sizes, int n_in,
                              void* d_out, int out_size, void* d_ws, size_t ws_size,
                              hipStream_t stream) {
    const float* x    = (const float*)d_in[0];
    const float* wemb = (const float*)d_in[1];
    const float* bemb = (const float*)d_in[2];
    const float* W1   = (const float*)d_in[3];
    const float* b1   = (const float*)d_in[4];
    const float* g1   = (const float*)d_in[5];
    const float* be1  = (const float*)d_in[6];
    const float* W2   = (const float*)d_in[7];
    const float* b2   = (const float*)d_in[8];
    const float* g2   = (const float*)d_in[9];
    const float* be2  = (const float*)d_in[10];
    const float* W3   = (const float*)d_in[11];
    const float* b3   = (const float*)d_in[12];
    const float* g3   = (const float*)d_in[13];
    const float* be3  = (const float*)d_in[14];
    const float* wp   = (const float*)d_in[15];
    const float* bp   = (const float*)d_in[16];

    char* base = (char*)d_ws;
    short* PA   = (short*)(base);                  // 16-ch vol: 19,906,560 B
    short* PB   = (short*)(base + 19906560);       // 16-ch vol: 19,906,560 B
    short* P32  = (short*)(base + 39813120);       // 2 vols: 39,813,120 B
    short* WB1  = (short*)(base + 79626240);       // 320,512 B
    short* WB2  = (short*)(base + 79946752);       // 641,024 B
    short* WB3  = (short*)(base + 80587776);       // 641,024 B
    float* ps   = (float*)(base + 81228800);       // 32*1024*4 = 131,072 B
    float* psq  = (float*)(base + 81359872);       // 131,072 B
    float* sc1  = (float*)(base + 81490944);       // 128 B each
    float* sh1  = (float*)(base + 81491072);
    float* sc2  = (float*)(base + 81491200);
    float* sh2  = (float*)(base + 81491328);
    float* sc3  = (float*)(base + 81491456);
    float* sh3  = (float*)(base + 81491584);

    // zero all padded activation volumes (pads must be 0 every call;
    // staging relies on it -> conv staging is a raw copy, no masking)
    hipMemsetAsync(base, 0, 79626240, stream);

    repack_bf16<<<(1 * 626 * 16 * 16 + 255) / 256, 256, 0, stream>>>(W1, WB1, 16, 1);
    repack_bf16<<<(1 * 626 * 32 * 16 + 255) / 256, 256, 0, stream>>>(W2, WB2, 32, 1);
    repack_bf16<<<(2 * 626 * 16 * 16 + 255) / 256, 256, 0, stream>>>(W3, WB3, 16, 2);

    embed_kernel<<<NPOS / 256, 256, 0, stream>>>(x, wemb, bemb, PA);

    // layer 1: 16 -> 16
    conv_mfma<16, 16><<<NCB, 256, 0, stream>>>(PA, WB1, b1, PB, ps, psq);
    stats_kernel<<<16, 256, 0, stream>>>(ps, psq, g1, be1, sc1, sh1);
    bn_lrelu16<<<2 * NPOS / 256, 256, 0, stream>>>(PB, sc1, sh1, 0);

    // layer 2: 16 -> 32 (output = 2 split 16-ch vols)
    conv_mfma<16, 32><<<NCB, 256, 0, stream>>>(PB, WB2, b2, P32, ps, psq);
    stats_kernel<<<32, 256, 0, stream>>>(ps, psq, g2, be2, sc2, sh2);
    bn_lrelu16<<<2 * NPOS / 256, 256, 0, stream>>>(P32, sc2, sh2, 0);
    bn_lrelu16<<<2 * NPOS / 256, 256, 0, stream>>>(P32 + VOLE, sc2, sh2, 16);

    // layer 3: 32 -> 16 (reads 2 split vols)
    conv_mfma<32, 16><<<NCB, 256, 0, stream>>>(P32, WB3, b3, PA, ps, psq);
    stats_kernel<<<16, 256, 0, stream>>>(ps, psq, g3, be3, sc3, sh3);

    // BN3 + lrelu + projection
    bnproj_kernel<<<NPOS / 256, 256, 0, stream>>>(PA, sc3, sh3, wp, bp, (float*)d_out);
}

// Round 9
// 511.791 us; speedup vs baseline: 1.2043x; 1.1953x over previous
//
#include <hip/hip_runtime.h>

#define LRELU_SLOPE 0.01f
#define BN_EPS 1e-5f

constexpr int B_ = 2, T_ = 8, Z_ = 16, Y_ = 32, X_ = 32;
constexpr int SP   = T_ * Z_ * Y_ * X_;   // 131072
constexpr int NPOS = B_ * SP;             // 262144
constexpr int Tp = 12, Zp = 20, Yp = 36, Xp = 36;   // padded dims (+2 each side)
constexpr int NCB  = 1024;                // conv blocks: b2 * t8 * z16 * yq4
constexpr size_t VOLE = (size_t)B_ * Tp * Zp * Yp * Xp * 16;  // shorts per 16-ch padded vol

typedef float v4f  __attribute__((ext_vector_type(4)));
typedef __bf16 v8bf __attribute__((ext_vector_type(8)));
typedef short  v8s  __attribute__((ext_vector_type(8)));

static __device__ __forceinline__ float bf2f(short s) {
    unsigned int u = ((unsigned int)(unsigned short)s) << 16;
    float f; __builtin_memcpy(&f, &u, 4); return f;
}
static __device__ __forceinline__ short f2bf(float f) {
    unsigned int u; __builtin_memcpy(&u, &f, 4);
    u += 0x7FFF + ((u >> 16) & 1);
    return (short)(u >> 16);
}
static __device__ __forceinline__ v4f mfma16(v8bf a, v8bf b, v4f c) {
    return __builtin_amdgcn_mfma_f32_16x16x32_bf16(a, b, c, 0, 0, 0);
}

// ------------------------------------------------------------ weight repack
// W[co][ci][625] fp32 -> WB[cih][o 626][co][16ci] bf16 (o==625 = zero block)
__global__ void repack_bf16(const float* __restrict__ W, short* __restrict__ WB,
                            int CO, int CIH) {
    int i = blockIdx.x * 256 + threadIdx.x;
    int total = CIH * 626 * CO * 16;
    if (i >= total) return;
    int cih = i / (626 * CO * 16);
    int r   = i % (626 * CO * 16);
    int o   = r / (CO * 16);
    int rr  = r % (CO * 16);
    int co = rr / 16, cil = rr % 16;
    WB[i] = (o == 625) ? (short)0
          : f2bf(W[((size_t)co * (CIH * 16) + cih * 16 + cil) * 625 + o]);
}

// ------------------------------------------------------------ embed -> padded bf16 channel-last
__global__ void embed_kernel(const float* __restrict__ x, const float* __restrict__ wemb,
                             const float* __restrict__ bemb, short* __restrict__ outp) {
    int g = blockIdx.x * 256 + threadIdx.x;
    const float* xr = x + (size_t)g * 8;
    float xv[8];
#pragma unroll
    for (int f = 0; f < 8; ++f) xv[f] = xr[f];
    int xx = g & 31, yy = (g >> 5) & 31, zz = (g >> 10) & 15, tt = (g >> 14) & 7, bb = g >> 17;
    size_t addr = ((((size_t)(bb * Tp + tt + 2) * Zp + zz + 2) * Yp + yy + 2) * Xp + xx + 2) * 16;
    short ov[16];
#pragma unroll
    for (int c = 0; c < 16; ++c) {
        float a = bemb[c];
#pragma unroll
        for (int f = 0; f < 8; ++f) a = fmaf(xv[f], wemb[f * 16 + c], a);
        ov[c] = f2bf(a);
    }
    *(v8s*)(outp + addr)     = *(v8s*)ov;
    *(v8s*)(outp + addr + 8) = *(v8s*)(ov + 8);
}

// ------------------------------------------------------------ conv4d: dbuf LDS slab, 1 barrier/phase
// Block (256 thr, 4 waves) = (b,t,z,yq): out y in [yq*8,+8), x 0..31, all CO.
// Slabs s=(kt,kz)[,cih]: 25*CIH planes of 12y x 36x x 16ci, raw-copied to LDS
// (pads pre-zeroed in global). Double-buffered: compute(s, buf s&1) while the
// single pf[4] register set carries slab s+1; write into buf (s+1)&1 (safe:
// its readers finished at the end-of-phase(s-1) barrier); ONE sync per phase.
// Wave = (xh, yw): 16x x 4y. Grid swizzle: blk&7 = t (XCD L2 locality).
template <int CI, int CO>
__global__ __launch_bounds__(256, 4) void conv_mfma(
        const short* __restrict__ inp,   // CIH padded vols, stride VOLE
        const short* __restrict__ wb,    // bf16 [CIH][626][CO][16]
        const float* __restrict__ bias,
        short* __restrict__ outp,        // NT padded vols, stride VOLE
        float* __restrict__ ps, float* __restrict__ psq) {
    constexpr int NT = CO / 16;
    constexpr int CIH = CI / 16;
    constexpr int NS = 25 * CIH;
    constexpr int SLAB = 12 * 36 * 16;           // 6912 shorts
    constexpr int SLABP = SLAB + 16;             // +16: dummy-lane read overflow
    __shared__ short As[2 * SLABP];
    __shared__ float lsum[32], lsq[32];

    const int tid = threadIdx.x;
    const int w = tid >> 6, lane = tid & 63;
    const int q = lane >> 4, m = lane & 15;
    const int xh = w & 1, yw = w >> 1;
    const int blk = blockIdx.x;
    const int t = blk & 7;                       // XCD swizzle
    const int loc = blk >> 3;
    const int yq = loc & 3, z = (loc >> 2) & 15, b = loc >> 6;

    const int ci0 = (q & 1) * 8;
    const int sel = q >> 1;

    if (tid < 4) *(v8s*)(As + (tid >> 1) * SLABP + SLAB + (tid & 1) * 8) =
        (v8s){0,0,0,0,0,0,0,0};

    v4f acc[4][NT];
#pragma unroll
    for (int al = 0; al < 4; ++al)
#pragma unroll
        for (int nt = 0; nt < NT; ++nt) acc[al][nt] = (v4f){0.f, 0.f, 0.f, 0.f};

    auto sdec = [&](int s, int& cih, int& kt, int& kz) {
        int sl = (CIH == 2) ? (s >> 1) : s;
        cih = (CIH == 2) ? (s & 1) : 0;
        kt = sl / 5; kz = sl % 5;
    };
    auto slab_ok = [&](int s) -> bool {
        int cih, kt, kz; sdec(s, cih, kt, kz);
        int tt = t + kt, zz = z + kz;
        return tt >= 2 && tt < 10 && zz >= 2 && zz < 18;
    };
    v8s pf[4];
    auto load_pf = [&](int s) {
        int cih, kt, kz; sdec(s, cih, kt, kz);
        const short* gA = inp + (size_t)cih * VOLE +
            (((size_t)(b * Tp + t + kt) * Zp + (z + kz)) * Yp + yq * 8) * (size_t)(Xp * 16);
#pragma unroll
        for (int r2 = 0; r2 < 4; ++r2) {
            int off = tid * 8 + r2 * 2048;
            if (off < SLAB) pf[r2] = *(const v8s*)(gA + off);
        }
    };
    auto write_pf = [&](int slot) {
#pragma unroll
        for (int r2 = 0; r2 < 4; ++r2) {
            int off = tid * 8 + r2 * 2048;
            if (off < SLAB) *(v8s*)(As + slot * SLABP + off) = pf[r2];
        }
    };

    if (slab_ok(0)) { load_pf(0); write_pf(0); }
    __syncthreads();

#pragma unroll 1
    for (int s = 0; s < NS; ++s) {
        const bool nok = (s + 1 < NS) && slab_ok(s + 1);
        if (nok) load_pf(s + 1);

        if (slab_ok(s)) {
            int cih, kt, kz; sdec(s, cih, kt, kz);
            const int obase = (kt * 5 + kz) * 25;
            const short* wbc = wb + (size_t)cih * 626 * (CO * 16);
            const short* Ab = As + (s & 1) * SLABP;
#pragma unroll
            for (int g = 0; g < 3; ++g) {
                const int kx0 = 2 * g;
                v8bf Bf[5][NT];
#pragma unroll
                for (int ky = 0; ky < 5; ++ky) {
                    const int o0 = obase + ky * 5 + kx0;
                    const int od = (g < 2) ? 1 : (625 - o0);
                    const int oq = o0 + sel * od;
#pragma unroll
                    for (int nt = 0; nt < NT; ++nt)
                        Bf[ky][nt] = *(const v8bf*)(wbc + (size_t)oq * (CO * 16) +
                                                    (nt * 16 + m) * 16 + ci0);
                }
                const int ax = xh * 16 + m + kx0 + sel;
#pragma unroll
                for (int rl = 0; rl < 8; ++rl) {
                    v8bf Af = *(const v8bf*)(Ab + ((yw * 4 + rl) * 36 + ax) * 16 + ci0);
#pragma unroll
                    for (int ky = 0; ky < 5; ++ky) {
                        const int al = rl - ky;
                        if (al >= 0 && al < 4) {
#pragma unroll
                            for (int nt = 0; nt < NT; ++nt)
                                acc[al][nt] = mfma16(Af, Bf[ky][nt], acc[al][nt]);
                        }
                    }
                }
            }
        }
        if (nok) write_pf((s + 1) & 1);
        __syncthreads();
    }

    // ---- epilogue: bias, bf16 store (raw) to NT padded vols, block stats
    if (tid < 32) { lsum[tid] = 0.f; lsq[tid] = 0.f; }
    __syncthreads();

    const int ybase = yq * 8 + yw * 4;
#pragma unroll
    for (int nt = 0; nt < NT; ++nt) {
        const int co = nt * 16 + m;
        const float bv = bias[co];
        float s = 0.f, sq = 0.f;
#pragma unroll
        for (int al = 0; al < 4; ++al) {
            const size_t orow = (size_t)nt * VOLE +
                ((((size_t)(b * Tp + t + 2) * Zp + (z + 2)) * Yp +
                  (ybase + al + 2)) * Xp + (xh * 16 + 2)) * 16;
#pragma unroll
            for (int rg = 0; rg < 4; ++rg) {
                float v = acc[al][nt][rg] + bv;
                outp[orow + (size_t)(q * 4 + rg) * 16 + m] = f2bf(v);
                s += v; sq += v * v;
            }
        }
        s += __shfl_down(s, 32, 64);  sq += __shfl_down(sq, 32, 64);
        s += __shfl_down(s, 16, 64);  sq += __shfl_down(sq, 16, 64);
        if (lane < 16) { atomicAdd(&lsum[co], s); atomicAdd(&lsq[co], sq); }
    }
    __syncthreads();
    if (tid < CO) {
        ps[(size_t)tid * NCB + blk]  = lsum[tid];
        psq[(size_t)tid * NCB + blk] = lsq[tid];
    }
}

// ------------------------------------------------------------ bn stats: fold into scale/shift
__global__ void stats_kernel(const float* __restrict__ ps, const float* __restrict__ psq,
                             const float* __restrict__ g, const float* __restrict__ beta,
                             float* __restrict__ scale, float* __restrict__ shift) {
    int co = blockIdx.x;
    int tid = threadIdx.x;
    float s = 0.f, q = 0.f;
    for (int i = tid; i < NCB; i += 256) {
        s += ps[(size_t)co * NCB + i];
        q += psq[(size_t)co * NCB + i];
    }
#pragma unroll
    for (int off = 32; off >= 1; off >>= 1) {
        s += __shfl_down(s, off, 64);
        q += __shfl_down(q, off, 64);
    }
    __shared__ float ss[4], qq[4];
    int w = tid >> 6, lane = tid & 63;
    if (lane == 0) { ss[w] = s; qq[w] = q; }
    __syncthreads();
    if (tid == 0) {
        float S = ss[0] + ss[1] + ss[2] + ss[3];
        float Q = qq[0] + qq[1] + qq[2] + qq[3];
        float mn = S / (float)NPOS;
        float var = Q / (float)NPOS - mn * mn;
        float rstd = rsqrtf(var + BN_EPS);
        float sc = g[co] * rstd;
        scale[co] = sc;
        shift[co] = beta[co] - mn * sc;
    }
}

// ------------------------------------------------------------ bn + leaky relu, in-place interior of one 16-ch vol
__global__ void bn_lrelu16(short* __restrict__ vol, const float* __restrict__ scale,
                           const float* __restrict__ shift, int coff) {
    int g = blockIdx.x * 256 + threadIdx.x;      // 0..2*NPOS-1
    int half = g & 1, p = g >> 1;
    int xx = p & 31, yy = (p >> 5) & 31, zz = (p >> 10) & 15, tt = (p >> 14) & 7, bb = p >> 17;
    size_t addr = ((((size_t)(bb * Tp + tt + 2) * Zp + zz + 2) * Yp + yy + 2) * Xp + xx + 2) * 16
                + half * 8;
    const int c0 = coff + half * 8;
    v8s v = *(v8s*)(vol + addr);
    short o[8];
#pragma unroll
    for (int j = 0; j < 8; ++j) {
        float f = bf2f(v[j]) * scale[c0 + j] + shift[c0 + j];
        f = f > 0.f ? f : LRELU_SLOPE * f;
        o[j] = f2bf(f);
    }
    *(v8s*)(vol + addr) = *(v8s*)o;
}

// ------------------------------------------------------------ final: bn3 + lrelu + projection
__global__ void bnproj_kernel(const short* __restrict__ h, const float* __restrict__ scale,
                              const float* __restrict__ shift, const float* __restrict__ wp,
                              const float* __restrict__ bp, float* __restrict__ out) {
    int g = blockIdx.x * 256 + threadIdx.x;
    int xx = g & 31, yy = (g >> 5) & 31, zz = (g >> 10) & 15, tt = (g >> 14) & 7, bb = g >> 17;
    size_t addr = ((((size_t)(bb * Tp + tt + 2) * Zp + zz + 2) * Yp + yy + 2) * Xp + xx + 2) * 16;
    v8s lo = *(const v8s*)(h + addr);
    v8s hi = *(const v8s*)(h + addr + 8);
    float a = bp[0];
#pragma unroll
    for (int j = 0; j < 8; ++j) {
        float f = bf2f(lo[j]) * scale[j] + shift[j];
        f = f > 0.f ? f : LRELU_SLOPE * f;
        a = fmaf(f, wp[j], a);
    }
#pragma unroll
    for (int j = 0; j < 8; ++j) {
        float f = bf2f(hi[j]) * scale[8 + j] + shift[8 + j];
        f = f > 0.f ? f : LRELU_SLOPE * f;
        a = fmaf(f, wp[8 + j], a);
    }
    out[g] = a;
}

// ------------------------------------------------------------ launch
extern "C" void kernel_launch(void* const* d_in, const int* in_sizes, int n_in,
                              void* d_out, int out_size, void* d_ws, size_t ws_size,
                              hipStream_t stream) {
    const float* x    = (const float*)d_in[0];
    const float* wemb = (const float*)d_in[1];
    const float* bemb = (const float*)d_in[2];
    const float* W1   = (const float*)d_in[3];
    const float* b1   = (const float*)d_in[4];
    const float* g1   = (const float*)d_in[5];
    const float* be1  = (const float*)d_in[6];
    const float* W2   = (const float*)d_in[7];
    const float* b2   = (const float*)d_in[8];
    const float* g2   = (const float*)d_in[9];
    const float* be2  = (const float*)d_in[10];
    const float* W3   = (const float*)d_in[11];
    const float* b3   = (const float*)d_in[12];
    const float* g3   = (const float*)d_in[13];
    const float* be3  = (const float*)d_in[14];
    const float* wp   = (const float*)d_in[15];
    const float* bp   = (const float*)d_in[16];

    char* base = (char*)d_ws;
    short* PA   = (short*)(base);                  // 16-ch vol: 19,906,560 B
    short* PB   = (short*)(base + 19906560);       // 16-ch vol: 19,906,560 B
    short* P32  = (short*)(base + 39813120);       // 2 vols: 39,813,120 B
    short* WB1  = (short*)(base + 79626240);       // 320,512 B
    short* WB2  = (short*)(base + 79946752);       // 641,024 B
    short* WB3  = (short*)(base + 80587776);       // 641,024 B
    float* ps   = (float*)(base + 81228800);       // 32*1024*4 = 131,072 B
    float* psq  = (float*)(base + 81359872);       // 131,072 B
    float* sc1  = (float*)(base + 81490944);       // 128 B each
    float* sh1  = (float*)(base + 81491072);
    float* sc2  = (float*)(base + 81491200);
    float* sh2  = (float*)(base + 81491328);
    float* sc3  = (float*)(base + 81491456);
    float* sh3  = (float*)(base + 81491584);

    // zero all padded activation volumes (pads must be 0 every call;
    // staging relies on it -> conv staging is a raw copy, no masking)
    hipMemsetAsync(base, 0, 79626240, stream);

    repack_bf16<<<(1 * 626 * 16 * 16 + 255) / 256, 256, 0, stream>>>(W1, WB1, 16, 1);
    repack_bf16<<<(1 * 626 * 32 * 16 + 255) / 256, 256, 0, stream>>>(W2, WB2, 32, 1);
    repack_bf16<<<(2 * 626 * 16 * 16 + 255) / 256, 256, 0, stream>>>(W3, WB3, 16, 2);

    embed_kernel<<<NPOS / 256, 256, 0, stream>>>(x, wemb, bemb, PA);

    // layer 1: 16 -> 16
    conv_mfma<16, 16><<<NCB, 256, 0, stream>>>(PA, WB1, b1, PB, ps, psq);
    stats_kernel<<<16, 256, 0, stream>>>(ps, psq, g1, be1, sc1, sh1);
    bn_lrelu16<<<2 * NPOS / 256, 256, 0, stream>>>(PB, sc1, sh1, 0);

    // layer 2: 16 -> 32 (output = 2 split 16-ch vols)
    conv_mfma<16, 32><<<NCB, 256, 0, stream>>>(PB, WB2, b2, P32, ps, psq);
    stats_kernel<<<32, 256, 0, stream>>>(ps, psq, g2, be2, sc2, sh2);
    bn_lrelu16<<<2 * NPOS / 256, 256, 0, stream>>>(P32, sc2, sh2, 0);
    bn_lrelu16<<<2 * NPOS / 256, 256, 0, stream>>>(P32 + VOLE, sc2, sh2, 16);

    // layer 3: 32 -> 16 (reads 2 split vols)
    conv_mfma<32, 16><<<NCB, 256, 0, stream>>>(P32, WB3, b3, PA, ps, psq);
    stats_kernel<<<16, 256, 0, stream>>>(ps, psq, g3, be3, sc3, sh3);

    // BN3 + lrelu + projection
    bnproj_kernel<<<NPOS / 256, 256, 0, stream>>>(PA, sc3, sh3, wp, bp, (float*)d_out);
}